// Round 2
// baseline (138.042 us; speedup 1.0000x reference)
//
#include <hip/hip_runtime.h>
#include <math.h>

#define KEYS 11
#define NSTACK 4
#define NB 16
#define HH 128
#define WW 128
#define HW (HH * WW)          // 16384 floats per slice
#define CHUNKS 4              // chunks per slice
#define CHUNK_F4 1024         // float4s per chunk (4096 floats)
#define NSLICE (NB * NSTACK * KEYS)   // 704
#define NPART (NSLICE * CHUNKS)       // 2816

// ws layout (float/int elements, 4096-elem aligned regions):
//   wsum  : ws[0      .. 2816)
//   wvmax : ws[4096   .. 4096+2816)
//   wimax : ((int*)ws)[8192 .. 8192+2816)

__global__ __launch_bounds__(256) void kp_partial_kernel(
    const float* __restrict__ cp,    // (16, 4, 22, 128, 128)
    const float* __restrict__ heat,  // (16, 11, 128, 128)
    float* __restrict__ ws)
{
    const int bid   = blockIdx.x;     // slice*4 + chunk
    const int c     = bid & 3;
    const int slice = bid >> 2;       // bs*11 + k
    const int k  = slice % KEYS;
    const int bs = slice / KEYS;      // b*4 + s
    const int b  = bs >> 2;

    const float4* __restrict__ hm4 = (const float4*)(cp + ((size_t)(bs * (2 * KEYS) + k)) * HW);
    const float4* __restrict__ ht4 = (const float4*)(heat + ((size_t)(b * KEYS + k)) * HW);

    const int tid = threadIdx.x;
    float sum  = 0.0f;
    float vmax = -INFINITY;
    int   imax = 0;

    #pragma unroll
    for (int j = 0; j < 4; j++) {
        int i = c * CHUNK_F4 + tid + j * 256;   // float4 index within slice
        float4 a = hm4[i];
        float4 h = ht4[i];
        float d0 = a.x - h.x, d1 = a.y - h.y, d2 = a.z - h.z, d3 = a.w - h.w;
        sum += d0 * d0 + d1 * d1 + d2 * d2 + d3 * d3;
        int base = i * 4;                        // global in-slice scalar index
        // strictly-greater keeps the first occurrence (indices ascend per thread)
        if (a.x > vmax) { vmax = a.x; imax = base;     }
        if (a.y > vmax) { vmax = a.y; imax = base + 1; }
        if (a.z > vmax) { vmax = a.z; imax = base + 2; }
        if (a.w > vmax) { vmax = a.w; imax = base + 3; }
    }

    // wave-64 reduction (sum + argmax, first-index tie break)
    #pragma unroll
    for (int off = 32; off > 0; off >>= 1) {
        float ov = __shfl_down(vmax, off);
        int   oi = __shfl_down(imax, off);
        float os = __shfl_down(sum,  off);
        sum += os;
        if (ov > vmax || (ov == vmax && oi < imax)) { vmax = ov; imax = oi; }
    }

    __shared__ float s_sum[4];
    __shared__ float s_v[4];
    __shared__ int   s_i[4];
    const int wave = tid >> 6;
    if ((tid & 63) == 0) { s_sum[wave] = sum; s_v[wave] = vmax; s_i[wave] = imax; }
    __syncthreads();

    if (tid == 0) {
        #pragma unroll
        for (int w = 1; w < 4; w++) {
            sum += s_sum[w];
            if (s_v[w] > vmax || (s_v[w] == vmax && s_i[w] < imax)) {
                vmax = s_v[w]; imax = s_i[w];
            }
        }
        ws[bid]        = sum;
        ws[4096 + bid] = vmax;
        ((int*)ws)[8192 + bid] = imax;
    }
}

__global__ __launch_bounds__(768) void kp_final_kernel(
    const float* __restrict__ cp,
    const float* __restrict__ lab,   // (16, 11, 11)
    const float* __restrict__ ws,
    float* __restrict__ out)         // 128: heat_loss(64) then label_loss(64)
{
    __shared__ float sh[NSLICE];   // per-slice heat partial
    __shared__ float sl[NSLICE];   // per-slice label partial

    const int t = threadIdx.x;
    if (t < NSLICE) {
        const int slice = t;
        const int k  = slice % KEYS;
        const int bs = slice / KEYS;
        const int b  = bs >> 2;

        // combine 4 chunk partials in chunk order (preserves first-index tie break)
        float sum  = 0.0f;
        float vmax = -INFINITY;
        int   imax = 0;
        #pragma unroll
        for (int c = 0; c < CHUNKS; c++) {
            int p = slice * CHUNKS + c;
            float v = ws[4096 + p];
            if (v > vmax) { vmax = v; imax = ((const int*)ws)[8192 + p]; }
            sum += ws[p];
        }
        sh[t] = sum;

        // label loss for this (b, s, k)
        const float* __restrict__ L  = lab + (size_t)(b * KEYS + k) * 11;
        float gx = L[9], gy = L[10];
        float loss = 0.0f;
        if ((gx > 0.0f) && (gy > 0.0f) && (gx < (float)HH) && (gy < (float)WW)) {
            const float* __restrict__ lb =
                cp + ((size_t)(bs * (2 * KEYS) + KEYS + k)) * HW;
            float xf = (float)(imax / WW);   // x = index // m (m == 128)
            float yf = (float)(imax % WW);   // y = index %  m
            float dx = gx + L[7] - xf - lb[7];
            float dy = gy + L[8] - yf - lb[8];
            loss = dx * dx + dy * dy;
            float cm = 1.0f - vmax;
            loss += cm * cm;
            #pragma unroll
            for (int j = 0; j < 7; j++) {
                float d = lb[j] - L[j];
                loss += d * d;
            }
        }
        sl[t] = loss;
    }
    __syncthreads();

    if (t < 64) {   // t == bs
        float a = 0.0f, c = 0.0f;
        #pragma unroll
        for (int k = 0; k < KEYS; k++) {
            a += sh[t * KEYS + k];
            c += sl[t * KEYS + k];
        }
        out[t]      = a;
        out[64 + t] = c;
    }
}

extern "C" void kernel_launch(void* const* d_in, const int* in_sizes, int n_in,
                              void* d_out, int out_size, void* d_ws, size_t ws_size,
                              hipStream_t stream) {
    const float* cp   = (const float*)d_in[0];
    const float* heat = (const float*)d_in[1];
    const float* lab  = (const float*)d_in[2];
    float* out = (float*)d_out;
    float* ws  = (float*)d_ws;

    kp_partial_kernel<<<NPART, 256, 0, stream>>>(cp, heat, ws);
    kp_final_kernel<<<1, 768, 0, stream>>>(cp, lab, ws, out);
}